// Round 4
// baseline (945.628 us; speedup 1.0000x reference)
//
#include <hip/hip_runtime.h>
#include <math.h>

// ---------------------------------------------------------------------------
// IPOT on MI355X — round 9.
// Math (exact, verified in R1-R8):
//   Cl = -C;  M_t = exp((t+1)*Cl)
//   row:  r_i = sum_j M_t(i,j) s_j ; a = 1/(n r)
//   col:  c_j = sum_i M_t(i,j) a_i ; b = 1/c (2^10 inj); s' = b^2/b_prev/1024
//   final G(A,B) = (1/(256*1024)) sum_k P(k,A) R(k,B)
// R9 (R5-R8 invariant ~5us/iter isolated to VGPR SPILL: VGPR_Count=64 with
//     64 live floats of C/E -> scratch traffic on every phase):
//   - amdgpu_waves_per_eu(4,4) pins 4 waves/EU -> 128 VGPR budget; C/E and
//     vals[] stay in registers (verify: VGPR_Count ~120).
//   - 2-hop sync: sign-parity-tagged DATA stores (even t -> -v, odd -> +v;
//     all col partials > 0; 3-buffer rotation, same-address coherence =>
//     stale values always fail parity). No flags, no producer drain barrier,
//     no wave-0 poll. Consumer: one-shot 32-load readback + SELECTIVE retry
//     of tag-failed slots only (fixed slot-order sum, static vals[] indices
//     -> registers). Bit-identical association to R7 (absmax 0.0).
//   - k_gemm: 512 threads (4x2 micro), same 64x64 tile -> 2 waves/SIMD
//     (was 1); identical k-order per dot -> bit-identical C.
// ---------------------------------------------------------------------------

#define NWG 32
#define TPB 1024
#define NIT 50

// ws offsets in floats
constexpr int CL_OFF   = 0;              // -C [1024*1024]
constexpr int CVEC_OFF = 1024 * 1024;    // [3][NWG][1024] tagged col partials
// total ~ 4.4 MB

// ---------------- C = 1 - xhat yhat^T (norms fused) ; Cl = -C ---------------
__global__ __launch_bounds__(512) void k_gemm(const float* __restrict__ X,
                                              const float* __restrict__ Y,
                                              float* __restrict__ ws) {
    __shared__ float As[32][68];
    __shared__ float Bs[32][68];
    __shared__ float nX[64], nY[64];
    float* Cl = ws + CL_OFF;

    int tid = threadIdx.x;
    int tx = tid & 31, ty = tid >> 5;   // cols 2*tx.., rows 4*ty..
    int bx = blockIdx.x, by = blockIdx.y;
    int lr0 = tid >> 3;                 // 0..63 (row this thread stages)
    int kq  = (tid & 7) * 4;            // 0..28

    float acc[4][2] = {};
    float sx = 0.f, sy = 0.f;
    for (int k0 = 0; k0 < 512; k0 += 32) {
        float4 xa = *(const float4*)(X + (size_t)(by * 64 + lr0) * 512 + k0 + kq);
        float4 ya = *(const float4*)(Y + (size_t)(bx * 64 + lr0) * 512 + k0 + kq);
        sx += xa.x * xa.x + xa.y * xa.y + xa.z * xa.z + xa.w * xa.w;
        sy += ya.x * ya.x + ya.y * ya.y + ya.z * ya.z + ya.w * ya.w;
        As[kq + 0][lr0] = xa.x; As[kq + 1][lr0] = xa.y;
        As[kq + 2][lr0] = xa.z; As[kq + 3][lr0] = xa.w;
        Bs[kq + 0][lr0] = ya.x; Bs[kq + 1][lr0] = ya.y;
        Bs[kq + 2][lr0] = ya.z; Bs[kq + 3][lr0] = ya.w;
        __syncthreads();
#pragma unroll
        for (int kk = 0; kk < 32; ++kk) {
            float4 a4 = *(const float4*)&As[kk][4 * ty];
            float2 b2 = *(const float2*)&Bs[kk][2 * tx];
            float av[4] = {a4.x, a4.y, a4.z, a4.w};
#pragma unroll
            for (int r = 0; r < 4; ++r) {
                acc[r][0] += av[r] * b2.x;
                acc[r][1] += av[r] * b2.y;
            }
        }
        __syncthreads();
    }
#pragma unroll
    for (int m = 1; m < 8; m <<= 1) {
        sx += __shfl_xor(sx, m, 64);
        sy += __shfl_xor(sy, m, 64);
    }
    if ((tid & 7) == 0) { nX[lr0] = sx; nY[lr0] = sy; }
    __syncthreads();

    int i0 = by * 64 + 4 * ty, j0 = bx * 64 + 2 * tx;
    float vy0 = 1.0f / sqrtf(nY[2 * tx + 0]);
    float vy1 = 1.0f / sqrtf(nY[2 * tx + 1]);
#pragma unroll
    for (int r = 0; r < 4; ++r) {
        float vx = 1.0f / sqrtf(nX[4 * ty + r]);
        float2 o;
        o.x = acc[r][0] * vx * vy0 - 1.0f;  // Cl = dot - 1 = -C
        o.y = acc[r][1] * vx * vy1 - 1.0f;
        *(float2*)(Cl + (size_t)(i0 + r) * 1024 + j0) = o;
    }
}

// ---------------------- persistent IPOT iteration --------------------------
__global__ __launch_bounds__(1024)
__attribute__((amdgpu_waves_per_eu(4, 4)))
void k_ipot(float* __restrict__ ws, float* __restrict__ out) {
    __shared__ float sLp[1056];        // s (loop) / b (epilogue): [u][l], stride 66
    __shared__ float buf[16 * 1056];   // col partials [wave][u*66+lane]; epi Ps/Rs
    __shared__ float twv[16];

    const int g = blockIdx.x, tid = threadIdx.x;
    const int rs = tid >> 6, lane = tid & 63;   // wave id (0..15) / lane
    const int uo = tid & 15, lo = tid >> 4;     // owned col tid = lo*16+uo
    float* Cl   = ws + CL_OFF;
    float* cvec = ws + CVEC_OFF;

    // thread owns rows g*32 + rs*2 + i (i<2), cols lane*16 + u (u<16)
    float C[2][16], E[2][16];
#pragma unroll
    for (int i = 0; i < 2; ++i) {
        const float* src = Cl + (size_t)(g * 32 + rs * 2 + i) * 1024 + lane * 16;
#pragma unroll
        for (int q = 0; q < 4; ++q) {
            float4 c = *(const float4*)(src + 4 * q);
            C[i][4 * q + 0] = c.x; C[i][4 * q + 1] = c.y;
            C[i][4 * q + 2] = c.z; C[i][4 * q + 3] = c.w;
        }
    }
#pragma unroll
    for (int i = 0; i < 2; ++i)
#pragma unroll
        for (int u = 0; u < 16; ++u) E[i][u] = __expf(C[i][u]);  // round 0

    float bv = 1.0f;            // b_prev for owned col (= tid)
    float a0 = 0.0f, a1 = 0.0f; // this wave's row scalings (all lanes)

    for (int t = 0; t < NIT; ++t) {
        float sval;
        if (t == 0) {
            sval = 1.0f / 1024.0f;
        } else {
            // tag-polled readback of iter t-1 partials; selective retry
            const float* rb = cvec + ((t - 1) % 3) * (NWG * 1024) + tid;
            const bool expneg = ((t - 1) & 1) == 0;  // even iter stored -v
            float vals[32];
            unsigned pend = 0xffffffffu;
            long gd = 0;
            for (;;) {
#pragma unroll
                for (int s2 = 0; s2 < NWG; ++s2) {
                    if (pend & (1u << s2)) {
                        float v = __hip_atomic_load(rb + s2 * 1024, __ATOMIC_RELAXED,
                                                    __HIP_MEMORY_SCOPE_AGENT);
                        unsigned bits = __float_as_uint(v);
                        bool ok = expneg ? (bits > 0x80000000u)
                                         : (bits != 0u && bits < 0x80000000u);
                        if (ok) { vals[s2] = v; pend &= ~(1u << s2); }
                    }
                }
                if (!pend) break;
                if (++gd > 300000) break;  // anti-hang bailout
                __builtin_amdgcn_s_sleep(1);
            }
            float ssum = 0.0f;
#pragma unroll
            for (int s2 = 0; s2 < NWG; ++s2) ssum += vals[s2];
            float c = expneg ? -ssum : ssum;
            float b = 1.0f / c;
            sval = b * b / bv * (1.0f / 1024.0f);  // 2^-10 inj
            bv = b;
        }
        sLp[uo * 66 + lo] = sval;   // s for col tid at [tid&15][tid>>4]
        __syncthreads();

        // row phase: rp[i] = sum_u E[i][u] * s[lane*16+u]; xor-reduce -> all lanes
        float sv[16];
#pragma unroll
        for (int u = 0; u < 16; ++u) sv[u] = sLp[u * 66 + lane];
        float rp0 = 0.0f, rp1 = 0.0f;
#pragma unroll
        for (int u = 0; u < 16; ++u) {
            rp0 += E[0][u] * sv[u];
            rp1 += E[1][u] * sv[u];
        }
#pragma unroll
        for (int m = 1; m < 64; m <<= 1) {
            rp0 += __shfl_xor(rp0, m, 64);
            rp1 += __shfl_xor(rp1, m, 64);
        }
        a0 = 1.0f / (1024.0f * rp0);
        a1 = 1.0f / (1024.0f * rp1);

        // col phase: this wave's 2-row partials for its 16 cols (padded layout)
#pragma unroll
        for (int u = 0; u < 16; ++u)
            buf[rs * 1056 + u * 66 + lane] = E[0][u] * a0 + E[1][u] * a1;
        __syncthreads();

        // owner (col tid): sum 16 wave-partials, TAGGED plain store to slot g
        float csum = 0.0f;
#pragma unroll
        for (int w = 0; w < 16; ++w) csum += buf[w * 1056 + uo * 66 + lo];
        float tagged = (t & 1) ? csum : -csum;  // odd -> +, even -> -
        __hip_atomic_store(cvec + (t % 3) * (NWG * 1024) + g * 1024 + tid, tagged,
                           __ATOMIC_RELAXED, __HIP_MEMORY_SCOPE_AGENT);

        // recompute E for next round (overlaps store->load sync latency)
        if (t < NIT - 1) {
            const float kf = (float)(t + 2);
#pragma unroll
            for (int i = 0; i < 2; ++i)
#pragma unroll
                for (int u = 0; u < 16; ++u) E[i][u] = __expf(kf * C[i][u]);
        }
    }

    // ------------- epilogue: E = exp(50*Cl), a0/a1 = round-49 a -------------
    {   // tag-polled readback of iter-49 partials (odd -> positive tags)
        const float* rb = cvec + ((NIT - 1) % 3) * (NWG * 1024) + tid;
        float vals[32];
        unsigned pend = 0xffffffffu;
        long gd = 0;
        for (;;) {
#pragma unroll
            for (int s2 = 0; s2 < NWG; ++s2) {
                if (pend & (1u << s2)) {
                    float v = __hip_atomic_load(rb + s2 * 1024, __ATOMIC_RELAXED,
                                                __HIP_MEMORY_SCOPE_AGENT);
                    unsigned bits = __float_as_uint(v);
                    if (bits != 0u && bits < 0x80000000u) {
                        vals[s2] = v; pend &= ~(1u << s2);
                    }
                }
            }
            if (!pend) break;
            if (++gd > 300000) break;
            __builtin_amdgcn_s_sleep(1);
        }
        float ssum = 0.0f;
#pragma unroll
        for (int s2 = 0; s2 < NWG; ++s2) ssum += vals[s2];
        sLp[uo * 66 + lo] = 1.0f / ssum;   // b for col tid
    }
    __syncthreads();

    // P(k,A=lane) and R(k,B=lane) for this thread's 2 rows (A-block == lane)
    float* Ps = buf;          // [32][64]
    float* Rs = buf + 2048;   // [32][64]
    float bl[16];
#pragma unroll
    for (int u = 0; u < 16; ++u) bl[u] = sLp[u * 66 + lane];
    {
        float p0 = 0.0f, r0 = 0.0f, p1 = 0.0f, r1 = 0.0f;
#pragma unroll
        for (int u = 0; u < 16; ++u) {
            p0 += C[0][u]; r0 += E[0][u] * bl[u];
            p1 += C[1][u]; r1 += E[1][u] * bl[u];
        }
        Ps[(rs * 2 + 0) * 64 + lane] = -p0;            // C = -Cl
        Rs[(rs * 2 + 0) * 64 + lane] = a0 * r0;
        Ps[(rs * 2 + 1) * 64 + lane] = -p1;
        Rs[(rs * 2 + 1) * 64 + lane] = a1 * r1;
    }
    __syncthreads();

    // G partial (this WG's 32 k-rows) -> atomicAdd into zeroed d_out
    float Rk[32];
#pragma unroll
    for (int k = 0; k < 32; ++k) Rk[k] = Rs[k * 64 + lane];  // B = lane
    const float sc = 1.0f / (256.0f * 1024.0f);
    float tsum = 0.0f;
#pragma unroll
    for (int q = 0; q < 4; ++q) {
        int o = tid + 1024 * q;
        int A = o >> 6;  // = rs + 16*q
        float acc = 0.0f;
#pragma unroll
        for (int k = 0; k < 32; ++k) acc += Ps[k * 64 + A] * Rk[k];
        float val = acc * sc;
        atomicAdd(out + o, val);
        if (A == lane) tsum += val;
    }
#pragma unroll
    for (int m = 1; m < 64; m <<= 1) tsum += __shfl_xor(tsum, m, 64);
    if (lane == 0) twv[rs] = tsum;
    __syncthreads();
    if (tid == 0) {
        float ts = 0.0f;
#pragma unroll
        for (int w = 0; w < 16; ++w) ts += twv[w];
        atomicAdd(out + 4096, ts);
    }
}

// ---------------------------------------------------------------------------
extern "C" void kernel_launch(void* const* d_in, const int* in_sizes, int n_in,
                              void* d_out, int out_size, void* d_ws, size_t ws_size,
                              hipStream_t stream) {
    const float* X = (const float*)d_in[0];  // t_prob [1024,512]
    const float* Y = (const float*)d_in[1];  // v_prob [1024,512]
    float* out = (float*)d_out;              // [64*64 + 1]
    float* ws  = (float*)d_ws;

    // zero cvec (tags rely on clean zeros; ws poisoned each call) + d_out
    (void)hipMemsetAsync((char*)d_ws + (size_t)CVEC_OFF * 4, 0,
                         (size_t)(3 * NWG * 1024) * 4, stream);
    (void)hipMemsetAsync(d_out, 0, (size_t)out_size * 4, stream);

    k_gemm<<<dim3(16, 16), 512, 0, stream>>>(X, Y, ws);
    k_ipot<<<NWG, TPB, 0, stream>>>(ws, out);
}

// Round 5
// 332.006 us; speedup vs baseline: 2.8482x; 2.8482x over previous
//
#include <hip/hip_runtime.h>
#include <math.h>

// ---------------------------------------------------------------------------
// IPOT on MI355X — round 10.
// Math (exact, verified in R1-R9):
//   Cl = -C;  M_t = exp((t+1)*Cl)
//   row:  r_i = sum_j M_t(i,j) s_j ; a = 1/(n r)
//   col:  c_j = sum_i M_t(i,j) a_i ; b = 1/c (2^10 inj); s' = b^2/b_prev/1024
//   final G(A,B) = (1/(256*1024)) sum_k P(k,A) R(k,B)
// R10 (R9 showed attr ignored, VGPR stuck at 64 -> spill persists; per-thread
//      polling re-regressed. Fix spill structurally, keep best-measured sync):
//   - C[2][16] dropped from registers: E-recompute reloads Cl from global
//     (L2-resident slab) in the post-add skew shadow; epilogue row-sums
//     p0/p1 precomputed at init. Live set ~57 floats -> fits 64 VGPRs.
//   - LDS padded to 82272B (>81920B) -> 1 WG/CU -> backend occupancy target
//     4 waves/EU -> 128-VGPR budget (belt-and-braces vs allocator). Runtime
//     occupancy unchanged (32 WGs on 256 CUs = 1 WG/CU anyway).
//   - Sync = R6's exact best-measured protocol: NREP=4 atomicAdd replicas,
//     tid0 polls 4 group counters, 4-load readback, rotating zero pass.
//   - R8's conflict-free padded LDS layouts + in-register a0/a1 kept.
// ---------------------------------------------------------------------------

#define NWG 32
#define TPB 1024
#define NIT 50
#define NREP 4

typedef unsigned long long ull;

// ws offsets in floats
constexpr int CL_OFF   = 0;                           // -C [1024*1024]
constexpr int CVEC_OFF = 1024 * 1024;                 // [3][NREP][1024]
constexpr int CNT_OFF  = CVEC_OFF + 3 * NREP * 1024;  // 4 group counters (pad 16)
// total ~ 4.05 MB

// ---------------- C = 1 - xhat yhat^T (norms fused) ; Cl = -C ---------------
__global__ __launch_bounds__(512) void k_gemm(const float* __restrict__ X,
                                              const float* __restrict__ Y,
                                              float* __restrict__ ws) {
    __shared__ float As[32][68];
    __shared__ float Bs[32][68];
    __shared__ float nX[64], nY[64];
    float* Cl = ws + CL_OFF;

    int tid = threadIdx.x;
    int tx = tid & 31, ty = tid >> 5;   // cols 2*tx.., rows 4*ty..
    int bx = blockIdx.x, by = blockIdx.y;
    int lr0 = tid >> 3;                 // 0..63 (row this thread stages)
    int kq  = (tid & 7) * 4;            // 0..28

    float acc[4][2] = {};
    float sx = 0.f, sy = 0.f;
    for (int k0 = 0; k0 < 512; k0 += 32) {
        float4 xa = *(const float4*)(X + (size_t)(by * 64 + lr0) * 512 + k0 + kq);
        float4 ya = *(const float4*)(Y + (size_t)(bx * 64 + lr0) * 512 + k0 + kq);
        sx += xa.x * xa.x + xa.y * xa.y + xa.z * xa.z + xa.w * xa.w;
        sy += ya.x * ya.x + ya.y * ya.y + ya.z * ya.z + ya.w * ya.w;
        As[kq + 0][lr0] = xa.x; As[kq + 1][lr0] = xa.y;
        As[kq + 2][lr0] = xa.z; As[kq + 3][lr0] = xa.w;
        Bs[kq + 0][lr0] = ya.x; Bs[kq + 1][lr0] = ya.y;
        Bs[kq + 2][lr0] = ya.z; Bs[kq + 3][lr0] = ya.w;
        __syncthreads();
#pragma unroll
        for (int kk = 0; kk < 32; ++kk) {
            float4 a4 = *(const float4*)&As[kk][4 * ty];
            float2 b2 = *(const float2*)&Bs[kk][2 * tx];
            float av[4] = {a4.x, a4.y, a4.z, a4.w};
#pragma unroll
            for (int r = 0; r < 4; ++r) {
                acc[r][0] += av[r] * b2.x;
                acc[r][1] += av[r] * b2.y;
            }
        }
        __syncthreads();
    }
#pragma unroll
    for (int m = 1; m < 8; m <<= 1) {
        sx += __shfl_xor(sx, m, 64);
        sy += __shfl_xor(sy, m, 64);
    }
    if ((tid & 7) == 0) { nX[lr0] = sx; nY[lr0] = sy; }
    __syncthreads();

    int i0 = by * 64 + 4 * ty, j0 = bx * 64 + 2 * tx;
    float vy0 = 1.0f / sqrtf(nY[2 * tx + 0]);
    float vy1 = 1.0f / sqrtf(nY[2 * tx + 1]);
#pragma unroll
    for (int r = 0; r < 4; ++r) {
        float vx = 1.0f / sqrtf(nX[4 * ty + r]);
        float2 o;
        o.x = acc[r][0] * vx * vy0 - 1.0f;  // Cl = dot - 1 = -C
        o.y = acc[r][1] * vx * vy1 - 1.0f;
        *(float2*)(Cl + (size_t)(i0 + r) * 1024 + j0) = o;
    }
}

// ---------------------- persistent IPOT iteration --------------------------
__global__ __launch_bounds__(1024)
__attribute__((amdgpu_waves_per_eu(1, 4)))
void k_ipot(float* __restrict__ ws, float* __restrict__ out) {
    __shared__ float sLp[1056];        // s (loop) / b (epilogue): [u][l], stride 66
    __shared__ float buf[16 * 1056];   // col partials [wave][u*66+lane]; epi Ps/Rs
    __shared__ float twv[16];
    __shared__ float pad[2600];        // occupancy shaper: LDS 82272B > 81920B
                                       // -> 1 WG/CU -> 4 waves/EU target
                                       // -> 128-VGPR allocator budget

    const int g = blockIdx.x, tid = threadIdx.x;
    const int rs = tid >> 6, lane = tid & 63;   // wave id (0..15) / lane
    const int uo = tid & 15, lo = tid >> 4;     // owned col tid = lo*16+uo
    float* Cl   = ws + CL_OFF;
    float* cvec = ws + CVEC_OFF;
    unsigned* grp = (unsigned*)(ws + CNT_OFF);

    pad[tid & 2047] = 0.0f;  // keep pad allocated; read (exact +0.0) at end

    // thread owns rows g*32 + rs*2 + i (i<2), cols lane*16 + u (u<16)
    const float* csrc0 = Cl + (size_t)(g * 32 + rs * 2 + 0) * 1024 + lane * 16;
    const float* csrc1 = csrc0 + 1024;

    float E[2][16];
    float p0 = 0.0f, p1 = 0.0f;   // rowsum(Cl) for epilogue (C not kept!)
#pragma unroll
    for (int q = 0; q < 4; ++q) {
        float4 c0 = *(const float4*)(csrc0 + 4 * q);
        float4 c1 = *(const float4*)(csrc1 + 4 * q);
        p0 += c0.x + c0.y + c0.z + c0.w;
        p1 += c1.x + c1.y + c1.z + c1.w;
        E[0][4 * q + 0] = __expf(c0.x); E[0][4 * q + 1] = __expf(c0.y);
        E[0][4 * q + 2] = __expf(c0.z); E[0][4 * q + 3] = __expf(c0.w);
        E[1][4 * q + 0] = __expf(c1.x); E[1][4 * q + 1] = __expf(c1.y);
        E[1][4 * q + 2] = __expf(c1.z); E[1][4 * q + 3] = __expf(c1.w);
    }

    float bv = 1.0f;            // b_prev for owned col (= tid)
    float a0 = 0.0f, a1 = 0.0f; // this wave's row scalings (all lanes)

    for (int t = 0; t < NIT; ++t) {
        float sval;
        if (t == 0) {
            sval = 1.0f / 1024.0f;
        } else {
            if (tid == 0) {  // poll: round t-1 adds complete everywhere
                unsigned tgt = (unsigned)t * 8u;
                long gd = 0;
                while (__hip_atomic_load(&grp[0], __ATOMIC_RELAXED, __HIP_MEMORY_SCOPE_AGENT) < tgt ||
                       __hip_atomic_load(&grp[1], __ATOMIC_RELAXED, __HIP_MEMORY_SCOPE_AGENT) < tgt ||
                       __hip_atomic_load(&grp[2], __ATOMIC_RELAXED, __HIP_MEMORY_SCOPE_AGENT) < tgt ||
                       __hip_atomic_load(&grp[3], __ATOMIC_RELAXED, __HIP_MEMORY_SCOPE_AGENT) < tgt) {
                    __builtin_amdgcn_s_sleep(1);
                    if (++gd > 2000000) break;  // anti-hang bailout
                }
            }
            __syncthreads();
            // one-shot guaranteed-ready readback: 4 replicas at own column
            const float* rb = cvec + ((t + 2) % 3) * (NREP * 1024) + tid;
            float r0 = __hip_atomic_load(rb + 0 * 1024, __ATOMIC_RELAXED, __HIP_MEMORY_SCOPE_AGENT);
            float r1 = __hip_atomic_load(rb + 1 * 1024, __ATOMIC_RELAXED, __HIP_MEMORY_SCOPE_AGENT);
            float r2 = __hip_atomic_load(rb + 2 * 1024, __ATOMIC_RELAXED, __HIP_MEMORY_SCOPE_AGENT);
            float r3 = __hip_atomic_load(rb + 3 * 1024, __ATOMIC_RELAXED, __HIP_MEMORY_SCOPE_AGENT);
            if (t >= 2 && tid < 64) {  // zero buffer (t+1)%3 (read at t-1, all done)
                ull* zb = (ull*)(cvec + ((t + 1) % 3) * (NREP * 1024)) + g * 64 + tid;
                __hip_atomic_store(zb, 0ull, __ATOMIC_RELAXED, __HIP_MEMORY_SCOPE_AGENT);
            }
            float c = r0 + r1 + r2 + r3;
            float b = 1.0f / c;
            sval = b * b / bv * (1.0f / 1024.0f);  // 2^-10 inj
            bv = b;
        }
        sLp[uo * 66 + lo] = sval;   // s for col tid at [tid&15][tid>>4]
        __syncthreads();

        // row phase: rp[i] = sum_u E[i][u] * s[lane*16+u]; xor-reduce -> all lanes
        float sv[16];
#pragma unroll
        for (int u = 0; u < 16; ++u) sv[u] = sLp[u * 66 + lane];
        float rp0 = 0.0f, rp1 = 0.0f;
#pragma unroll
        for (int u = 0; u < 16; ++u) {
            rp0 += E[0][u] * sv[u];
            rp1 += E[1][u] * sv[u];
        }
#pragma unroll
        for (int m = 1; m < 64; m <<= 1) {
            rp0 += __shfl_xor(rp0, m, 64);
            rp1 += __shfl_xor(rp1, m, 64);
        }
        a0 = 1.0f / (1024.0f * rp0);
        a1 = 1.0f / (1024.0f * rp1);

        // col phase: this wave's 2-row partials for its 16 cols (padded layout)
#pragma unroll
        for (int u = 0; u < 16; ++u)
            buf[rs * 1056 + u * 66 + lane] = E[0][u] * a0 + E[1][u] * a1;
        __syncthreads();

        // owner (col tid): sum 16 wave-partials, atomicAdd to replica g&3
        float csum = 0.0f;
#pragma unroll
        for (int w = 0; w < 16; ++w) csum += buf[w * 1056 + uo * 66 + lo];
        atomicAdd(cvec + (t % 3) * (NREP * 1024) + (g & 3) * 1024 + tid, csum);
        __syncthreads();  // per-thread vmcnt drain: adds + zero stores at LLC
        if (tid == 0)
            __hip_atomic_fetch_add(&grp[g >> 3], 1u, __ATOMIC_RELAXED,
                                   __HIP_MEMORY_SCOPE_AGENT);

        // recompute E for next round: reload Cl (L2-hot) in the skew shadow
        if (t < NIT - 1) {
            const float kf = (float)(t + 2);
#pragma unroll
            for (int q = 0; q < 4; ++q) {
                float4 c0 = *(const float4*)(csrc0 + 4 * q);
                float4 c1 = *(const float4*)(csrc1 + 4 * q);
                E[0][4 * q + 0] = __expf(kf * c0.x); E[0][4 * q + 1] = __expf(kf * c0.y);
                E[0][4 * q + 2] = __expf(kf * c0.z); E[0][4 * q + 3] = __expf(kf * c0.w);
                E[1][4 * q + 0] = __expf(kf * c1.x); E[1][4 * q + 1] = __expf(kf * c1.y);
                E[1][4 * q + 2] = __expf(kf * c1.z); E[1][4 * q + 3] = __expf(kf * c1.w);
            }
        }
    }

    // ------------- epilogue: E = exp(50*Cl), a0/a1 = round-49 a -------------
    if (tid == 0) {
        unsigned tgt = (unsigned)NIT * 8u;
        long gd = 0;
        while (__hip_atomic_load(&grp[0], __ATOMIC_RELAXED, __HIP_MEMORY_SCOPE_AGENT) < tgt ||
               __hip_atomic_load(&grp[1], __ATOMIC_RELAXED, __HIP_MEMORY_SCOPE_AGENT) < tgt ||
               __hip_atomic_load(&grp[2], __ATOMIC_RELAXED, __HIP_MEMORY_SCOPE_AGENT) < tgt ||
               __hip_atomic_load(&grp[3], __ATOMIC_RELAXED, __HIP_MEMORY_SCOPE_AGENT) < tgt) {
            __builtin_amdgcn_s_sleep(1);
            if (++gd > 2000000) break;
        }
    }
    __syncthreads();
    {   // final b for owned col: one-shot readback of iter-49 replicas
        const float* rb = cvec + ((NIT - 1) % 3) * (NREP * 1024) + tid;
        float r0 = __hip_atomic_load(rb + 0 * 1024, __ATOMIC_RELAXED, __HIP_MEMORY_SCOPE_AGENT);
        float r1 = __hip_atomic_load(rb + 1 * 1024, __ATOMIC_RELAXED, __HIP_MEMORY_SCOPE_AGENT);
        float r2 = __hip_atomic_load(rb + 2 * 1024, __ATOMIC_RELAXED, __HIP_MEMORY_SCOPE_AGENT);
        float r3 = __hip_atomic_load(rb + 3 * 1024, __ATOMIC_RELAXED, __HIP_MEMORY_SCOPE_AGENT);
        sLp[uo * 66 + lo] = 1.0f / (r0 + r1 + r2 + r3);   // b for col tid
    }
    __syncthreads();

    // P(k,A=lane) and R(k,B=lane) for this thread's 2 rows (A-block == lane)
    float* Ps = buf;          // [32][64]
    float* Rs = buf + 2048;   // [32][64]
    float bl[16];
#pragma unroll
    for (int u = 0; u < 16; ++u) bl[u] = sLp[u * 66 + lane];
    {
        float r0 = 0.0f, r1 = 0.0f;
#pragma unroll
        for (int u = 0; u < 16; ++u) {
            r0 += E[0][u] * bl[u];
            r1 += E[1][u] * bl[u];
        }
        Ps[(rs * 2 + 0) * 64 + lane] = -p0;            // C = -Cl, p = rowsum(Cl)
        Rs[(rs * 2 + 0) * 64 + lane] = a0 * r0;
        Ps[(rs * 2 + 1) * 64 + lane] = -p1;
        Rs[(rs * 2 + 1) * 64 + lane] = a1 * r1;
    }
    __syncthreads();

    // G partial (this WG's 32 k-rows) -> atomicAdd into zeroed d_out
    float Rk[32];
#pragma unroll
    for (int k = 0; k < 32; ++k) Rk[k] = Rs[k * 64 + lane];  // B = lane
    const float sc = 1.0f / (256.0f * 1024.0f);
    float tsum = pad[tid & 2047];   // exact +0.0; keeps pad live
#pragma unroll
    for (int q = 0; q < 4; ++q) {
        int o = tid + 1024 * q;
        int A = o >> 6;  // = rs + 16*q
        float acc = 0.0f;
#pragma unroll
        for (int k = 0; k < 32; ++k) acc += Ps[k * 64 + A] * Rk[k];
        float val = acc * sc;
        atomicAdd(out + o, val);
        if (A == lane) tsum += val;
    }
#pragma unroll
    for (int m = 1; m < 64; m <<= 1) tsum += __shfl_xor(tsum, m, 64);
    if (lane == 0) twv[rs] = tsum;
    __syncthreads();
    if (tid == 0) {
        float ts = 0.0f;
#pragma unroll
        for (int w = 0; w < 16; ++w) ts += twv[w];
        atomicAdd(out + 4096, ts);
    }
}

// ---------------------------------------------------------------------------
extern "C" void kernel_launch(void* const* d_in, const int* in_sizes, int n_in,
                              void* d_out, int out_size, void* d_ws, size_t ws_size,
                              hipStream_t stream) {
    const float* X = (const float*)d_in[0];  // t_prob [1024,512]
    const float* Y = (const float*)d_in[1];  // v_prob [1024,512]
    float* out = (float*)d_out;              // [64*64 + 1]
    float* ws  = (float*)d_ws;

    // zero cvec + counters (ws poisoned each call), zero d_out
    (void)hipMemsetAsync((char*)d_ws + (size_t)CVEC_OFF * 4, 0,
                         (size_t)(3 * NREP * 1024 + 16) * 4, stream);
    (void)hipMemsetAsync(d_out, 0, (size_t)out_size * 4, stream);

    k_gemm<<<dim3(16, 16), 512, 0, stream>>>(X, Y, ws);
    k_ipot<<<NWG, TPB, 0, stream>>>(ws, out);
}